// Round 1
// 25308.458 us; speedup vs baseline: 1.6771x; 1.6771x over previous
//
#include <hip/hip_runtime.h>
#include <hip/hip_bf16.h>

#define NB 64
#define NT 600
#define NTC 50
#define NH 400
#define NKATT 10
#define NALPHA 60
#define NOUT 121

typedef unsigned short u16;
typedef _Float16 f16x2 __attribute__((ext_vector_type(2)));
typedef _Float16 f16x4 __attribute__((ext_vector_type(4)));
typedef _Float16 f16x8 __attribute__((ext_vector_type(8)));

#if defined(__has_builtin)
#if __has_builtin(__builtin_amdgcn_fdot2)
#define FDOT2(a,b,c) __builtin_amdgcn_fdot2((a),(b),(c),false)
#endif
#endif
#ifndef FDOT2
#define FDOT2(a,b,c) ((c) + (float)(a)[0]*(float)(b)[0] + (float)(a)[1]*(float)(b)[1])
#endif

// Padded fused-K sizes (pairs): K1=512->256, K2=896->448, K3=1280->640. Rows padded 1600->1664.
#define ROWSP 1664

// Teams per batch-group (8 batches): 13 LSTM12 blocks + 13 LSTM3 blocks + 2 head blocks.
#define T1N 13
#define CGRP 15          // barC group: 13 team2 + 2 heads

// Ring-buffered cross-block state (floats).
#define H1R 0            // [4][NB][NH]
#define H2R 102400       // [4][NB][NH]
#define H3R 204800       // [2][NB][NH]
#define WINR 256000      // [4][NB][NALPHA]
#define ST_FLOATS 271360
#define SLOT_H 25600
#define SLOT_W 3840

// Team1 smem layout (bytes)
#define OF_WATT 0        // 25600 persistent W_att
#define OF_INB1 25600    // 8192  [8][256] pairs: h1(t) | win(t) | x(t+1) | 0-tail
#define OF_INB2 33792    // 14336 [8][448] pairs: h1 | h2p | win | x | 0-tail
#define OF_ACCS 48128    // 4608
#define OF_AB   52736    // 960
#define OF_PHI  53696    // 1600
#define OF_KAP  55296    // 320  persistent kappa
#define OF_CHS  55616    // 1600 persistent char seq
#define OF_LEN  57216    // 32
#define OF_C1   57248    // 1024 persistent c1
#define OF_C2   58272    // 1024 persistent c2
#define SMEM_TOTAL 59296
// Team2 smem: inb3 @0 (20480 = [8][640]), accS @20480 (4608), c3 @25088 (1024)
// Head smem:  zb @0 (9600), zv @9600 (1936)

__device__ __align__(16) f16x2 g_WT1[256 * ROWSP];
__device__ __align__(16) f16x2 g_WT2[448 * ROWSP];
__device__ __align__(16) f16x2 g_WT3[640 * ROWSP];
__device__ __align__(16) f16x2 g_WG8[150 * 128 * 4];  // [k8][r][j] f16x2 pairs
__device__ __align__(16) f16x2 g_WattP[200 * 32];
__device__ __align__(16) float g_fb1[ROWSP], g_fb2[ROWSP], g_fb3[ROWSP];
__device__ float g_batt[30], g_bgmm[121];
__device__ __align__(16) float g_inp[115200];
__device__ __align__(16) float g_state[ST_FLOATS];
__device__ unsigned int g_cnt[8 * 4 * 32];   // [bg][cid], one cacheline per counter
__device__ int g_isf32;

#define CNT_A 0   // team1 barA: bump after publishing h1(t); target 13*(t+1)
#define CNT_B 1   // team1:     bump after publishing h2(t);  target 13*(t+1)
#define CNT_C 2   // team2+heads barC(t): target 15*(t+1)

__device__ __forceinline__ float bf2f(u16 v) {
    union { unsigned int u; float f; } t; t.u = ((unsigned int)v) << 16; return t.f;
}
__device__ __forceinline__ u16 f2bf(float f) {
    union { float ff; unsigned int u; } t; t.ff = f;
    unsigned int lsb = (t.u >> 16) & 1u;
    t.u += 0x7fffu + lsb;
    return (u16)(t.u >> 16);
}
__device__ __forceinline__ float sigm(float x) { return 1.f / (1.f + expf(-x)); }
__device__ __forceinline__ f16x2 packpair(float a, float b) {
    f16x2 r; r[0] = (_Float16)a; r[1] = (_Float16)b; return r;
}

// ---- agent-scope (cross-XCD coherent, LLC-direct) state accessors ----
__device__ __forceinline__ void st_agent(float* p, float v) {
    __hip_atomic_store(p, v, __ATOMIC_RELAXED, __HIP_MEMORY_SCOPE_AGENT);
}
__device__ __forceinline__ float2 ld2_agent(const float* p) {
    unsigned long long u = __hip_atomic_load((const unsigned long long*)p,
                                             __ATOMIC_RELAXED, __HIP_MEMORY_SCOPE_AGENT);
    union { unsigned long long u; float2 f; } t; t.u = u; return t.f;
}
__device__ __forceinline__ unsigned ld_cnt(int bg, int cid) {
    return __hip_atomic_load(&g_cnt[(bg * 4 + cid) * 32], __ATOMIC_RELAXED, __HIP_MEMORY_SCOPE_AGENT);
}
// Precondition: a __syncthreads() (vmcnt-draining) precedes every bump in program order.
__device__ __forceinline__ void cnt_bump(int bg, int cid) {
    if (threadIdx.x == 0)
        __hip_atomic_fetch_add(&g_cnt[(bg * 4 + cid) * 32], 1u, __ATOMIC_RELAXED, __HIP_MEMORY_SCOPE_AGENT);
}
__device__ __forceinline__ void cnt_wait(int bg, int cid, unsigned tgt) {
    if (threadIdx.x == 0 && tgt > 0) {
        while (ld_cnt(bg, cid) < tgt) __builtin_amdgcn_s_sleep(1);
    }
    __syncthreads();
}

__global__ void k_detect(const void* whh1) {
    if (threadIdx.x == 0 && blockIdx.x == 0) {
        const u16* p = (const u16*)whh1;
        int f32 = 0;
        for (int k = 0; k < 256; ++k) {
            float v = bf2f(p[2 * k]);
            if (!(fabsf(v) < 1e3f)) f32 = 1;
        }
        g_isf32 = f32;
    }
}

// Build fused/transposed/permuted f16 weights + biases; canonicalize inputs; zero state.
__global__ void k_convert(const void* inp,
                          const void* wih1, const void* bih1, const void* whh1, const void* bhh1,
                          const void* wih2, const void* bih2, const void* whh2, const void* bhh2,
                          const void* wih3, const void* bih3, const void* whh3, const void* bhh3,
                          const void* watt, const void* batt, const void* wgmm, const void* bgmm)
{
    const int gt = blockIdx.x * blockDim.x + threadIdx.x;
    const int gs = gridDim.x * blockDim.x;
    const int f32 = g_isf32;
    auto ld = [f32](const void* p, int i) -> float {
        return f32 ? ((const float*)p)[i] : bf2f(((const u16*)p)[i]);
    };
    auto w1col = [&](int kf, int row) -> float {
        if (kf < 400) return ld(whh1, row * 400 + kf);
        if (kf < 460) return ld(wih1, row * 63 + (kf - 400));
        if (kf < 463) return ld(wih1, row * 63 + 60 + (kf - 460));
        return 0.f;
    };
    auto w2col = [&](int kf, int row) -> float {
        if (kf < 400) return ld(wih2, row * 463 + 3 + kf);
        if (kf < 800) return ld(whh2, row * 400 + (kf - 400));
        if (kf < 860) return ld(wih2, row * 463 + 403 + (kf - 800));
        if (kf < 863) return ld(wih2, row * 463 + (kf - 860));
        return 0.f;
    };
    auto w3col = [&](int kf, int row) -> float {
        if (kf < 400)  return ld(wih3, row * 863 + 3 + kf);
        if (kf < 800)  return ld(wih3, row * 863 + 403 + (kf - 400));
        if (kf < 1200) return ld(whh3, row * 400 + (kf - 800));
        if (kf < 1260) return ld(wih3, row * 863 + 803 + (kf - 1200));
        if (kf < 1263) return ld(wih3, row * 863 + (kf - 1260));
        return 0.f;
    };
    for (int i = gt; i < 256 * ROWSP; i += gs) {
        int k2 = i / ROWSP, rp = i % ROWSP;
        int j = rp >> 2, g = rp & 3;
        float a = 0.f, b = 0.f;
        if (j < 400) { int row = g * 400 + j; a = w1col(2 * k2, row); b = w1col(2 * k2 + 1, row); }
        g_WT1[i] = packpair(a, b);
    }
    for (int i = gt; i < 448 * ROWSP; i += gs) {
        int k2 = i / ROWSP, rp = i % ROWSP;
        int j = rp >> 2, g = rp & 3;
        float a = 0.f, b = 0.f;
        if (j < 400) { int row = g * 400 + j; a = w2col(2 * k2, row); b = w2col(2 * k2 + 1, row); }
        g_WT2[i] = packpair(a, b);
    }
    for (int i = gt; i < 640 * ROWSP; i += gs) {
        int k2 = i / ROWSP, rp = i % ROWSP;
        int j = rp >> 2, g = rp & 3;
        float a = 0.f, b = 0.f;
        if (j < 400) { int row = g * 400 + j; a = w3col(2 * k2, row); b = w3col(2 * k2 + 1, row); }
        g_WT3[i] = packpair(a, b);
    }
    for (int i = gt; i < ROWSP; i += gs) {
        int j = i >> 2, g = i & 3;
        float b1 = 0.f, b2 = 0.f, b3 = 0.f;
        if (j < 400) {
            int row = g * 400 + j;
            b1 = ld(bih1, row) + ld(bhh1, row);
            b2 = ld(bih2, row) + ld(bhh2, row);
            b3 = ld(bih3, row) + ld(bhh3, row);
        }
        g_fb1[i] = b1; g_fb2[i] = b2; g_fb3[i] = b3;
    }
    for (int i = gt; i < 200 * 32; i += gs) {        // W_att f16 pairs [k2][r]
        int k2 = i / 32, r = i % 32;
        float a = 0.f, b = 0.f;
        if (r < 30) { a = ld(watt, r * 400 + 2 * k2); b = ld(watt, r * 400 + 2 * k2 + 1); }
        g_WattP[i] = packpair(a, b);
    }
    for (int i = gt; i < 150 * 128 * 4; i += gs) {   // W_gmm f16x8-coalesced [k8][r][j]
        int k8 = i >> 9, rem = i & 511, r = rem >> 2, j = rem & 3;
        int kp = k8 * 4 + j;
        float a = 0.f, b = 0.f;
        if (r < 121) { a = ld(wgmm, r * 1200 + 2 * kp); b = ld(wgmm, r * 1200 + 2 * kp + 1); }
        g_WG8[i] = packpair(a, b);
    }
    for (int i = gt; i < 30; i += gs)  g_batt[i] = ld(batt, i);
    for (int i = gt; i < 121; i += gs) g_bgmm[i] = ld(bgmm, i);
    for (int i = gt; i < 115200; i += gs) g_inp[i] = ld(inp, i);
    for (int i = gt; i < ST_FLOATS; i += gs) g_state[i] = 0.f;
    for (int i = gt; i < 8 * 4 * 32; i += gs) g_cnt[i] = 0u;
}

// LSTM core: 8 waves split K in k4-groups; lane = 2 rowpairs x 8 batches.
// c-state in block-local LDS; h published to an LLC ring slot.
template<int KP2>
__device__ __forceinline__ void lstm_core(const f16x2* __restrict__ WT, const float* __restrict__ fb,
                                          float* __restrict__ cL, float* __restrict__ hdst,
                                          const f16x2* inb, float* accS, int rg, int bg, int tid)
{
    const int wv = tid >> 6, lane = tid & 63;
    const int ck4 = KP2 >> 5;
    const int k40 = wv * ck4;
    const int rbase = rg * 128 + lane * 2;
    float acc[2][8];
    #pragma unroll
    for (int r = 0; r < 2; ++r)
        #pragma unroll
        for (int b = 0; b < 8; ++b) acc[r][b] = 0.f;
    const f16x2* wp = WT + (size_t)(k40 * 4) * ROWSP + rbase;
    #pragma unroll 2
    for (int k4 = 0; k4 < ck4; ++k4) {
        f16x2 wa[4], wb[4];
        #pragma unroll
        for (int j = 0; j < 4; ++j) {
            union { f16x4 v; f16x2 p[2]; } u;
            u.v = *(const f16x4*)(wp + (size_t)j * ROWSP);
            wa[j] = u.p[0]; wb[j] = u.p[1];
        }
        #pragma unroll
        for (int b = 0; b < 8; ++b) {
            union { f16x8 v; f16x2 p[4]; } h;
            h.v = *(const f16x8*)(inb + b * KP2 + (k40 + k4) * 4);
            #pragma unroll
            for (int j = 0; j < 4; ++j) {
                acc[0][b] = FDOT2(wa[j], h.p[j], acc[0][b]);
                acc[1][b] = FDOT2(wb[j], h.p[j], acc[1][b]);
            }
        }
        wp += 4 * ROWSP;
    }
    #pragma unroll
    for (int r = 0; r < 2; ++r)
        #pragma unroll
        for (int b = 0; b < 8; ++b)
            atomicAdd(&accS[(lane * 2 + r) * 9 + b], acc[r][b]);
    __syncthreads();
    if (tid < 256) {
        int bl = tid >> 5, jj = tid & 31;
        int j = rg * 32 + jj;
        if (j < 400) {
            int rl = jj * 4;
            float gi = accS[(rl + 0) * 9 + bl] + fb[rg * 128 + rl + 0];
            float gf = accS[(rl + 1) * 9 + bl] + fb[rg * 128 + rl + 1];
            float gg = accS[(rl + 2) * 9 + bl] + fb[rg * 128 + rl + 2];
            float go = accS[(rl + 3) * 9 + bl] + fb[rg * 128 + rl + 3];
            float c = cL[bl * 32 + jj];
            float cn = sigm(gf) * c + sigm(gi) * tanhf(gg);
            cL[bl * 32 + jj] = cn;
            st_agent(&hdst[(bg * 8 + bl) * 400 + j], sigm(go) * tanhf(cn));
        }
    }
}

// GMM output head: 4 batches per block; h1/h2 from depth-4 ring, h3 from depth-2 ring.
__device__ void out_head(void* out, int t, int obid, int tid, char* smem)
{
    f16x2* zb = (f16x2*)smem;
    float* zv = (float*)(smem + 9600);
    const float* h1 = g_state + H1R + (t & 3) * SLOT_H;
    const float* h2 = g_state + H2R + (t & 3) * SLOT_H;
    const float* h3 = g_state + H3R + (t & 1) * SLOT_H;
    for (int i = tid; i < 4 * 600; i += 512) {
        int bq = i / 600, p = i % 600; int b = obid * 4 + bq;
        int kf = 2 * p;
        const float* src = (kf < 400) ? (h1 + b * 400 + kf)
                         : (kf < 800) ? (h2 + b * 400 + (kf - 400))
                                      : (h3 + b * 400 + (kf - 800));
        float2 hv = ld2_agent(src);
        zb[bq * 600 + p] = packpair(hv.x, hv.y);
    }
    __syncthreads();
    {
        int bq = tid >> 7, r = tid & 127;
        float ac0 = (r < 121) ? g_bgmm[r] : 0.f, ac1 = 0.f, ac2 = 0.f, ac3 = 0.f;
        const f16x8* zp = (const f16x8*)(zb + bq * 600);
        #pragma unroll 4
        for (int k8 = 0; k8 < 150; ++k8) {
            union { f16x8 v; f16x2 p[4]; } w, z;
            w.v = *(const f16x8*)&g_WG8[(k8 * 128 + r) * 4];
            z.v = zp[k8];
            ac0 = FDOT2(w.p[0], z.p[0], ac0);
            ac1 = FDOT2(w.p[1], z.p[1], ac1);
            ac2 = FDOT2(w.p[2], z.p[2], ac2);
            ac3 = FDOT2(w.p[3], z.p[3], ac3);
        }
        if (r < 121) zv[bq * 121 + r] = (ac0 + ac1) + (ac2 + ac3);
    }
    __syncthreads();
    if (tid < 484) {
        int bl = tid / 121, jo = tid - bl * 121;
        const float* z = zv + bl * 121;
        float val;
        if (jo < 20) {
            float m = -1e30f;
            for (int i = 0; i < 20; ++i) m = fmaxf(m, z[1 + i]);
            float s = 0.f;
            for (int i = 0; i < 20; ++i) s += expf(z[1 + i] - m);
            val = expf(z[1 + jo] - m) / s;
        } else if (jo < 60)  val = z[jo + 1];
        else if (jo < 100)   val = expf(z[jo + 1]);
        else if (jo < 120)   val = tanhf(z[jo + 1]);
        else                 val = 1.f / (1.f + expf(-z[0]));
        int idx = ((obid * 4 + bl) * NT + t) * NOUT + jo;
        if (g_isf32) ((float*)out)[idx] = val;
        else         ((u16*)out)[idx]  = f2bf(val);
    }
    __syncthreads();
}

// Persistent kernel. 224 blocks. XCD-affinity: x = bid&7.
// Team1 (13/bg): LSTM1 + attention + LSTM2; ONE spin barrier (barA) per step; LSTM2 runs
//   in the barrier-skew window (gated by counted cntB, no spin in steady state).
// Team2 (13/bg): LSTM3, chasing via cntB; barC shared with heads.
// Heads (2/bg): output GMM, after barC.
__global__ __launch_bounds__(512) void k_persist(void* out,
                                                 const int* __restrict__ cseq,
                                                 const int* __restrict__ clen)
{
    __shared__ __align__(16) char smem[SMEM_TOTAL];
    const int tid = threadIdx.x;
    const int bid = blockIdx.x;
    const int x = bid & 7, s = bid >> 3;
    int role, rg = 0, bg = 0, obid = 0;
    if (s < 8)       { role = 0; rg = x; bg = s; }
    else if (s < 13) { role = 0; int q = 5 * x + (s - 8);  rg = 8 + (q >> 3); bg = q & 7; }
    else if (s < 21) { role = 1; rg = x; bg = s - 13; }
    else if (s < 26) { role = 1; int q = 5 * x + (s - 21); rg = 8 + (q >> 3); bg = q & 7; }
    else             { role = 2; obid = 2 * x + (s - 26); bg = x; }

    if (role == 0) {
        // ---------------- Team1: LSTM1 + attention + LSTM2 ----------------
        f16x2* wattL = (f16x2*)(smem + OF_WATT);
        f16x2* inb1 = (f16x2*)(smem + OF_INB1);
        f16x2* inb2 = (f16x2*)(smem + OF_INB2);
        float* accS = (float*)(smem + OF_ACCS);
        float* ab  = (float*)(smem + OF_AB);
        float* phi = (float*)(smem + OF_PHI);
        float* kap = (float*)(smem + OF_KAP);
        int* chs = (int*)(smem + OF_CHS);
        int* len = (int*)(smem + OF_LEN);
        float* c1 = (float*)(smem + OF_C1);
        float* c2 = (float*)(smem + OF_C2);

        for (int i = tid; i < 200 * 32; i += 512) wattL[i] = g_WattP[i];
        for (int i = tid; i < 8 * 256; i += 512) inb1[i] = packpair(0.f, 0.f);
        for (int i = tid; i < 8 * 448; i += 512) inb2[i] = packpair(0.f, 0.f);
        for (int i = tid; i < 1152; i += 512) accS[i] = 0.f;
        if (tid < 80) kap[tid] = 0.f;
        if (tid >= 128 && tid < 384) { c1[tid - 128] = 0.f; c2[tid - 128] = 0.f; }
        for (int i = tid; i < 400; i += 512) chs[i] = cseq[(bg * 8 + i / 50) * NTC + i % 50];
        if (tid >= 384 && tid < 392) len[tid - 384] = clen[bg * 8 + (tid - 384)];
        if (tid < 16) {                                  // x(0)
            int bl = tid >> 1, hh = tid & 1, b = bg * 8 + bl;
            if (hh == 0) inb1[bl * 256 + 230] = packpair(g_inp[(b * NT) * 3 + 0], g_inp[(b * NT) * 3 + 1]);
            else         inb1[bl * 256 + 231] = packpair(g_inp[(b * NT) * 3 + 2], 0.f);
        }
        __syncthreads();
        // A(0): publish h1(0)
        lstm_core<256>(g_WT1, g_fb1, c1, g_state + H1R + 0 * SLOT_H, inb1, accS, rg, bg, tid);
        __syncthreads();
        cnt_bump(bg, CNT_A);

        for (int t = 0; t <= NT; ++t) {
            if (t >= 1) {
                // ---- B(t-1): LSTM2 for step t-1 (overlapped with barA(t) skew) ----
                for (int i = tid; i < 8 * 230; i += 512) {  // h1(t-1), win(t-1) from inb1
                    int bl = i / 230, p = i - bl * 230;
                    inb2[bl * 448 + (p < 200 ? p : p + 200)] = inb1[bl * 256 + p];
                }
                if (tid < 16) {                             // x(t-1)
                    int bl = tid >> 1, hh = tid & 1, b = bg * 8 + bl;
                    if (hh == 0) inb2[bl * 448 + 430] = packpair(g_inp[(b * NT + t - 1) * 3 + 0], g_inp[(b * NT + t - 1) * 3 + 1]);
                    else         inb2[bl * 448 + 431] = packpair(g_inp[(b * NT + t - 1) * 3 + 2], 0.f);
                }
                for (int i = tid; i < 1152; i += 512) accS[i] = 0.f;
                cnt_wait(bg, CNT_B, 13u * (unsigned)(t - 1));   // h2(t-2) published by all; instant in steady state
                const float* h2s = g_state + H2R + ((t - 2) & 3) * SLOT_H;
                for (int i = tid; i < 8 * 200; i += 512) {
                    int bl = i / 200, p = i - bl * 200, b = bg * 8 + bl;
                    float2 hv = ld2_agent(h2s + b * 400 + 2 * p);
                    inb2[bl * 448 + 200 + p] = packpair(hv.x, hv.y);
                }
                __syncthreads();
                lstm_core<448>(g_WT2, g_fb2, c2, g_state + H2R + ((t - 1) & 3) * SLOT_H, inb2, accS, rg, bg, tid);
                __syncthreads();
                cnt_bump(bg, CNT_B);
                if (t == NT) break;
            }
            // ---- barA(t) + ring throttle (team2/heads within 2 steps) ----
            if (tid == 0) {
                unsigned tgtA = 13u * (unsigned)(t + 1);
                while (ld_cnt(bg, CNT_A) < tgtA) __builtin_amdgcn_s_sleep(1);
                if (t >= 2) {
                    unsigned tgtC = 15u * (unsigned)(t - 1);
                    while (ld_cnt(bg, CNT_C) < tgtC) __builtin_amdgcn_s_sleep(1);
                }
            }
            __syncthreads();
            // ---- gather h1(t) into inb1 (also serves A(t+1) and att) ----
            const float* h1s = g_state + H1R + (t & 3) * SLOT_H;
            for (int i = tid; i < 8 * 200; i += 512) {
                int bl = i / 200, p = i - bl * 200, b = bg * 8 + bl;
                float2 hv = ld2_agent(h1s + b * 400 + 2 * p);
                inb1[bl * 256 + p] = packpair(hv.x, hv.y);
            }
            __syncthreads();
            // ---- attention: p = exp(h1 @ W_att.T + b_att) ----
            if (tid < 240) {
                int bl = tid / 30, rr = tid - bl * 30;
                float a0 = g_batt[rr], a1 = 0.f;
                const f16x2* hp = inb1 + bl * 256;
                #pragma unroll 4
                for (int k2 = 0; k2 < 200; k2 += 2) {
                    a0 = FDOT2(wattL[(k2 + 0) * 32 + rr], hp[k2 + 0], a0);
                    a1 = FDOT2(wattL[(k2 + 1) * 32 + rr], hp[k2 + 1], a1);
                }
                ab[bl * 30 + rr] = expf(a0 + a1);
            }
            __syncthreads();
            if (tid < 400) {                    // phi (length-masked)
                int bl = tid / 50, u = tid - bl * 50;
                float ph = 0.f;
                if (u < len[bl]) {
                    float uf = (float)u;
                    for (int k = 0; k < 10; ++k) {
                        float kn = kap[bl * 10 + k] + ab[bl * 30 + 20 + k];
                        float d = kn - uf;
                        ph += ab[bl * 30 + k] * expf(-ab[bl * 30 + 10 + k] * d * d);
                    }
                }
                phi[bl * 50 + u] = ph;
            }
            __syncthreads();
            if (tid < 240) {                    // window -> inb1 (+ ring publish by rg0)
                int bl = tid / 30, q = tid - bl * 30;
                int a0i = 2 * q, a1i = 2 * q + 1;
                float w0 = 0.f, w1 = 0.f;
                for (int u = 0; u < NTC; ++u) {
                    float pv = phi[bl * 50 + u]; int cc = chs[bl * 50 + u];
                    if (cc == a0i) w0 += pv;
                    if (cc == a1i) w1 += pv;
                }
                inb1[bl * 256 + 200 + q] = packpair(w0, w1);
                if (rg == 0) {
                    float* wr = g_state + WINR + (t & 3) * SLOT_W + (bg * 8 + bl) * 60;
                    st_agent(wr + a0i, w0); st_agent(wr + a1i, w1);
                }
            } else if (tid >= 256 && tid < 336) {   // kappa update (LDS-resident)
                int i = tid - 256; int bl = i / 10, k = i - bl * 10;
                kap[bl * 10 + k] += ab[bl * 30 + 20 + k];
            }
            if (t + 1 < NT && tid < 16) {           // x(t+1)
                int bl = tid >> 1, hh = tid & 1, b = bg * 8 + bl;
                if (hh == 0) inb1[bl * 256 + 230] = packpair(g_inp[(b * NT + t + 1) * 3 + 0], g_inp[(b * NT + t + 1) * 3 + 1]);
                else         inb1[bl * 256 + 231] = packpair(g_inp[(b * NT + t + 1) * 3 + 2], 0.f);
            }
            __syncthreads();
            // ---- A(t+1): publish h1(t+1), arrive barA(t+1) ----
            if (t + 1 < NT) {
                for (int i = tid; i < 1152; i += 512) accS[i] = 0.f;
                __syncthreads();
                lstm_core<256>(g_WT1, g_fb1, c1, g_state + H1R + ((t + 1) & 3) * SLOT_H, inb1, accS, rg, bg, tid);
                __syncthreads();
                cnt_bump(bg, CNT_A);
            }
        }
    } else if (role == 1) {
        // ---------------- Team2: LSTM3 (chases team1 via cntB) ----------------
        f16x2* inb3 = (f16x2*)smem;
        float* accS = (float*)(smem + 20480);
        float* c3 = (float*)(smem + 25088);
        for (int i = tid; i < 8 * 640; i += 512) inb3[i] = packpair(0.f, 0.f);
        if (tid < 256) c3[tid] = 0.f;
        __syncthreads();
        for (int t = 0; t < NT; ++t) {
            if (tid < 16) {                         // x(t)
                int bl = tid >> 1, hh = tid & 1, b = bg * 8 + bl;
                if (hh == 0) inb3[bl * 640 + 630] = packpair(g_inp[(b * NT + t) * 3 + 0], g_inp[(b * NT + t) * 3 + 1]);
                else         inb3[bl * 640 + 631] = packpair(g_inp[(b * NT + t) * 3 + 2], 0.f);
            }
            for (int i = tid; i < 1152; i += 512) accS[i] = 0.f;
            cnt_wait(bg, CNT_B, 13u * (unsigned)(t + 1));   // h2(t), win(t) (and h1(t), earlier) published
            const float* h1s = g_state + H1R + (t & 3) * SLOT_H;
            const float* h2s = g_state + H2R + (t & 3) * SLOT_H;
            const float* h3s = g_state + H3R + ((t - 1) & 1) * SLOT_H;
            const float* ws  = g_state + WINR + (t & 3) * SLOT_W;
            for (int i = tid; i < 8 * 630; i += 512) {
                int bl = i / 630, p = i - bl * 630, b = bg * 8 + bl;
                const float* src = (p < 200) ? h1s + b * 400 + 2 * p
                                 : (p < 400) ? h2s + b * 400 + 2 * (p - 200)
                                 : (p < 600) ? h3s + b * 400 + 2 * (p - 400)
                                             : ws  + b * 60  + 2 * (p - 600);
                float2 hv = ld2_agent(src);
                inb3[bl * 640 + p] = packpair(hv.x, hv.y);
            }
            __syncthreads();
            lstm_core<640>(g_WT3, g_fb3, c3, g_state + H3R + (t & 1) * SLOT_H, inb3, accS, rg, bg, tid);
            __syncthreads();
            cnt_bump(bg, CNT_C);                         // arrive barC(t)
            cnt_wait(bg, CNT_C, 15u * (unsigned)(t + 1)); // wait barC(t): keeps h3 ping safe vs heads
        }
    } else {
        // ---------------- Heads: output GMM ----------------
        for (int t = 0; t < NT; ++t) {
            cnt_bump(bg, CNT_C);                          // arrive barC(t) (done reading step t-1)
            cnt_wait(bg, CNT_C, 15u * (unsigned)(t + 1)); // wait barC(t): h3(t) ready
            out_head(out, t, obid, tid, smem);
        }
    }
}

extern "C" void kernel_launch(void* const* d_in, const int* in_sizes, int n_in,
                              void* d_out, int out_size, void* d_ws, size_t ws_size,
                              hipStream_t stream)
{
    hipLaunchKernelGGL(k_detect, dim3(1), dim3(64), 0, stream, d_in[5]);  // W_hh1
    hipLaunchKernelGGL(k_convert, dim3(2048), dim3(256), 0, stream,
                       d_in[0],
                       d_in[3], d_in[4], d_in[5], d_in[6],
                       d_in[7], d_in[8], d_in[9], d_in[10],
                       d_in[11], d_in[12], d_in[13], d_in[14],
                       d_in[15], d_in[16], d_in[17], d_in[18]);
    void* outp = d_out;
    const int* cseq = (const int*)d_in[1];
    const int* clen = (const int*)d_in[2];
    void* args[] = { (void*)&outp, (void*)&cseq, (void*)&clen };
    hipLaunchCooperativeKernel((void*)k_persist, dim3(224), dim3(512), args, 0, stream);
}